// Round 5
// baseline (181.867 us; speedup 1.0000x reference)
//
#include <hip/hip_runtime.h>

#define N_TASKS 8
#define ROW 24            // floats per pred/targ/R row
#define ROWB 96           // bytes per row
#define TILE 64           // rows per wave-tile
#define QROWB 36          // bytes per Q row

// LDS float4 indices: pred rows [0,512), R rows [512,1024), Q linear [1024,1168)
#define PRED0 0
#define R0    512
#define Q0    1024
#define LDSN  1168        // 18688 B -> 8 blocks/CU

// lane-contiguous float4 loads of one 64-row tile into named reg sets
#define LOADSET(P, T, RR, Q, TI) do {                                          \
    const char* _p = (const char*)pred + (size_t)(TI) * (TILE * ROWB);         \
    const char* _t = (const char*)targ + (size_t)(TI) * (TILE * ROWB);         \
    const char* _r = (const char*)Rm   + (size_t)(TI) * (TILE * ROWB);         \
    const char* _q = (const char*)Qm   + (size_t)(TI) * (TILE * QROWB);        \
    _Pragma("unroll")                                                          \
    for (int _j = 0; _j < 6; ++_j) {                                           \
        P[_j]  = *(const float4*)(_p + (_j * 64 + l) * 16);                    \
        T[_j]  = *(const float4*)(_t + (_j * 64 + l) * 16);                    \
        RR[_j] = *(const float4*)(_r + (_j * 64 + l) * 16);                    \
    }                                                                          \
    Q[0] = *(const float4*)(_q + l * 16);                                      \
    Q[1] = *(const float4*)(_q + (64 + l) * 16);                               \
    Q[2] = *(const float4*)(_q + (128 + (l & 15)) * 16);                       \
} while (0)

// stage one set into LDS (pred/R padded+XOR-swizzled rows, Q linear)
#define STORESET(P, RR, Q) do {                                                \
    _Pragma("unroll")                                                          \
    for (int _j = 0; _j < 6; ++_j) {                                           \
        lds[PRED0 + waddr[_j]] = P[_j];                                        \
        lds[R0    + waddr[_j]] = RR[_j];                                       \
    }                                                                          \
    lds[Q0 + l]      = Q[0];                                                   \
    lds[Q0 + 64 + l] = Q[1];                                                   \
    if (l < 16) lds[Q0 + 128 + l] = Q[2];                                      \
} while (0)

// flat-domain softplus + dot from regs (elementwise; no LDS needed)
#define FLATSET(P, T) do {                                                     \
    float _f0 = 0.0f, _f1 = 0.0f;                                              \
    _Pragma("unroll")                                                          \
    for (int _j = 0; _j < 6; ++_j) {                                           \
        float4 _x = P[_j], _y = T[_j];                                         \
        _f0 += fmaxf(_x.x, 0.0f) + __logf(1.0f + __expf(-fabsf(_x.x))) - _x.x * _y.x; \
        _f1 += fmaxf(_x.y, 0.0f) + __logf(1.0f + __expf(-fabsf(_x.y))) - _x.y * _y.y; \
        _f0 += fmaxf(_x.z, 0.0f) + __logf(1.0f + __expf(-fabsf(_x.z))) - _x.z * _y.z; \
        _f1 += fmaxf(_x.w, 0.0f) + __logf(1.0f + __expf(-fabsf(_x.w))) - _x.w * _y.w; \
    }                                                                          \
    base_acc += (double)(_f0 + _f1);                                           \
} while (0)

// row-domain capability term from LDS (lane l owns row l)
#define ROWCAP() do {                                                          \
    float pv[ROW], rv[ROW];                                                    \
    _Pragma("unroll")                                                          \
    for (int _s = 0; _s < 6; ++_s) {                                           \
        float4 _v = lds[PRED0 + 8 * l + (_s ^ key)];                           \
        pv[4 * _s + 0] = _v.x; pv[4 * _s + 1] = _v.y;                          \
        pv[4 * _s + 2] = _v.z; pv[4 * _s + 3] = _v.w;                          \
        float4 _w = lds[R0 + 8 * l + (_s ^ key)];                              \
        rv[4 * _s + 0] = _w.x; rv[4 * _s + 1] = _w.y;                          \
        rv[4 * _s + 2] = _w.z; rv[4 * _s + 3] = _w.w;                          \
    }                                                                          \
    const float* _qf = (const float*)&lds[Q0];                                 \
    float qv[9];                                                               \
    _Pragma("unroll")                                                          \
    for (int _e = 0; _e < 9; ++_e) qv[_e] = _qf[9 * l + _e];                   \
    float _cap = 0.0f;                                                         \
    _Pragma("unroll")                                                          \
    for (int _tk = 0; _tk < N_TASKS; ++_tk) {                                  \
        float _p0 = pv[_tk * 3 + 0];                                           \
        float _p1 = pv[_tk * 3 + 1];                                           \
        float _p2 = pv[_tk * 3 + 2];                                           \
        float _a0 = (_p0 > 0.5f) ? 1.0f : 0.0f;                                \
        float _a1 = (_p1 > 0.5f) ? 1.0f : 0.0f;                                \
        float _a2 = (_p2 > 0.5f) ? 1.0f : 0.0f;                                \
        float _tc0 = _a0 * qv[0] + _a1 * qv[3] + _a2 * qv[6];                  \
        float _tc1 = _a0 * qv[1] + _a1 * qv[4] + _a2 * qv[7];                  \
        float _tc2 = _a0 * qv[2] + _a1 * qv[5] + _a2 * qv[8];                  \
        float _sh  = fmaxf(rv[_tk * 3 + 0] - _tc0, 0.0f)                       \
                   + fmaxf(rv[_tk * 3 + 1] - _tc1, 0.0f)                       \
                   + fmaxf(rv[_tk * 3 + 2] - _tc2, 0.0f);                      \
        bool _active = (_p0 + _p1 + _p2) > 0.0f;                               \
        _cap += _active ? _sh : 0.0f;                                          \
    }                                                                          \
    cap_acc += (double)_cap;                                                   \
} while (0)

// ---------------------------------------------------------------------------
// Stage 1: one wave per block, contiguous tile spans, reg-staged LDS
// transpose, depth-1 software pipeline (loads of t+1 under compute of t).
// No barriers, no global_load_lds, no hand-rolled waitcnt: the compiler
// emits counted vmcnt/lgkmcnt for register/memory deps.
// ---------------------------------------------------------------------------
__global__ __launch_bounds__(64, 2) void mrta_partial_kernel(
    const float* __restrict__ pred,
    const float* __restrict__ targ,
    const float* __restrict__ Rm,
    const float* __restrict__ Qm,
    double* __restrict__ partials,
    int B)
{
    __shared__ __align__(16) float4 lds[LDSN];

    const int l = threadIdx.x;   // 0..63

    // flat chunk g = 64j + l -> row r = g/6, slot s = g%6, phys 8r + (s^(r&7))
    int waddr[6];
#pragma unroll
    for (int j = 0; j < 6; ++j) {
        int g = 64 * j + l;
        int r = g / 6, s = g - 6 * r;
        waddr[j] = 8 * r + (s ^ (r & 7));
    }
    const int key = l & 7;

    double base_acc = 0.0, cap_acc = 0.0;

    const int ntiles = B / TILE;
    const int G = gridDim.x;
    const int tpb = ntiles / G, rem = ntiles % G;
    const int start = blockIdx.x * tpb + (blockIdx.x < rem ? blockIdx.x : rem);
    const int cnt = tpb + (blockIdx.x < rem ? 1 : 0);

    float4 pA[6], tA[6], rA[6], qA[3];
    float4 pB[6], tB[6], rB[6], qB[3];

    if (cnt > 0) LOADSET(pA, tA, rA, qA, start);

    int i = 0;
    for (; i + 2 <= cnt; i += 2) {
        // ---- tile i (set A) ----
        STORESET(pA, rA, qA);
        LOADSET(pB, tB, rB, qB, start + i + 1);   // prefetch t+1 under compute
        FLATSET(pA, tA);
        ROWCAP();
        // ---- tile i+1 (set B) ----
        STORESET(pB, rB, qB);
        if (i + 2 < cnt) LOADSET(pA, tA, rA, qA, start + i + 2);
        FLATSET(pB, tB);
        ROWCAP();
    }
    if (i < cnt) {            // odd remainder tile (set A)
        STORESET(pA, rA, qA);
        FLATSET(pA, tA);
        ROWCAP();
    }

    // ---- tail rows (B % 64), scalar, block 0 only ----
    if (blockIdx.x == 0) {
        int row = ntiles * TILE + l;
        if (row < B) {
            const float* pr = pred + (size_t)row * ROW;
            const float* tr = targ + (size_t)row * ROW;
            const float* rr = Rm   + (size_t)row * ROW;
            const float* qr = Qm   + (size_t)row * 9;
            float base = 0.0f;
            float pv[ROW];
            for (int k = 0; k < ROW; ++k) {
                float x = pr[k];
                pv[k] = x;
                base += fmaxf(x, 0.0f) + __logf(1.0f + __expf(-fabsf(x))) - x * tr[k];
            }
            float cap = 0.0f;
            for (int tk = 0; tk < N_TASKS; ++tk) {
                float p0 = pv[tk * 3 + 0], p1 = pv[tk * 3 + 1], p2 = pv[tk * 3 + 2];
                float a0 = (p0 > 0.5f) ? 1.0f : 0.0f;
                float a1 = (p1 > 0.5f) ? 1.0f : 0.0f;
                float a2 = (p2 > 0.5f) ? 1.0f : 0.0f;
                float tc0 = a0 * qr[0] + a1 * qr[3] + a2 * qr[6];
                float tc1 = a0 * qr[1] + a1 * qr[4] + a2 * qr[7];
                float tc2 = a0 * qr[2] + a1 * qr[5] + a2 * qr[8];
                float sh  = fmaxf(rr[tk * 3 + 0] - tc0, 0.0f)
                          + fmaxf(rr[tk * 3 + 1] - tc1, 0.0f)
                          + fmaxf(rr[tk * 3 + 2] - tc2, 0.0f);
                if ((p0 + p1 + p2) > 0.0f) cap += sh;
            }
            base_acc += (double)base;
            cap_acc  += (double)cap;
        }
    }

    // ---- wave reduction, one partial pair per block ----
#pragma unroll
    for (int off = 32; off > 0; off >>= 1) {
        base_acc += __shfl_down(base_acc, off);
        cap_acc  += __shfl_down(cap_acc, off);
    }
    if (l == 0) {
        partials[blockIdx.x]             = base_acc;
        partials[gridDim.x + blockIdx.x] = cap_acc;
    }
}

// ---------------------------------------------------------------------------
// Stage 2: single-block deterministic reduction + final scalar math.
// out = {total_loss, base_loss, cap_violation, 0}
// ---------------------------------------------------------------------------
__global__ __launch_bounds__(256) void mrta_final_kernel(
    const double* __restrict__ partials,
    int nparts,
    float* __restrict__ out,
    double inv_BM,   // 1 / (B * 24)
    double inv_B)    // 1 / B
{
    double b = 0.0, c = 0.0;
    for (int i = threadIdx.x; i < nparts; i += 256) {
        b += partials[i];
        c += partials[nparts + i];
    }
#pragma unroll
    for (int off = 32; off > 0; off >>= 1) {
        b += __shfl_down(b, off);
        c += __shfl_down(c, off);
    }
    __shared__ double sb[4];
    __shared__ double sc[4];
    const int wave = threadIdx.x >> 6;
    const int lane = threadIdx.x & 63;
    if (lane == 0) { sb[wave] = b; sc[wave] = c; }
    __syncthreads();
    if (threadIdx.x == 0) {
        double bsum = sb[0] + sb[1] + sb[2] + sb[3];
        double csum = sc[0] + sc[1] + sc[2] + sc[3];
        double base = bsum * inv_BM;
        double cap  = csum * inv_B;
        double tot  = base + 0.1 * cap;
        out[0] = (float)tot;
        out[1] = (float)base;
        out[2] = (float)cap;
        out[3] = 0.0f;
    }
}

extern "C" void kernel_launch(void* const* d_in, const int* in_sizes, int n_in,
                              void* d_out, int out_size, void* d_ws, size_t ws_size,
                              hipStream_t stream) {
    const float* pred = (const float*)d_in[0];
    const float* targ = (const float*)d_in[1];
    const float* Rm   = (const float*)d_in[2];
    const float* Qm   = (const float*)d_in[3];
    float* out = (float*)d_out;

    const int B = in_sizes[0] / ROW;  // 2097152

    int blocks = 4096;
    if ((size_t)(2 * blocks) * sizeof(double) > ws_size) {
        blocks = (int)(ws_size / (2 * sizeof(double)));
        if (blocks > 4096) blocks = 4096;
        if (blocks < 1) blocks = 1;
    }

    double* partials = (double*)d_ws;

    mrta_partial_kernel<<<blocks, 64, 0, stream>>>(pred, targ, Rm, Qm, partials, B);
    mrta_final_kernel<<<1, 256, 0, stream>>>(partials, blocks, out,
                                             1.0 / ((double)B * ROW),
                                             1.0 / (double)B);
}

// Round 6
// 125.520 us; speedup vs baseline: 1.4489x; 1.4489x over previous
//
#include <hip/hip_runtime.h>

#define N_TASKS 8
#define ROW 24            // floats per pred/targ/R row
#define ROWB 96           // bytes per row
#define TILE 32           // rows per wave-tile
#define QROWB 36          // bytes per Q row

typedef __attribute__((address_space(3))) void* lds_ptr_t;
typedef const __attribute__((address_space(1))) void* gbl_ptr_t;

// Per-buffer LDS layout (float4 slots): pred [0,256) padded+swizzled,
// R [256,512) padded+swizzled, Q [512,592) linear. 592*16 = 9472 B/buffer,
// x2 buffers = 18944 B/block -> 8 blocks/CU.
#define PRED0 0
#define R0    256
#define Q0    512
#define BUFSZ 592

#define SB0 __builtin_amdgcn_sched_barrier(0)
#define WAITV13 do { asm volatile("s_waitcnt vmcnt(13)" ::: "memory"); } while (0)
#define WAITV0  do { asm volatile("s_waitcnt vmcnt(0)"  ::: "memory"); } while (0)

// 10 global_load_lds per stage: 4 pred + 4 R + 2 Q
#define STAGE(TI, BSEL) do {                                                   \
    const char* _pT = (const char*)pred + (size_t)(TI) * (TILE * ROWB);        \
    const char* _rT = (const char*)Rm   + (size_t)(TI) * (TILE * ROWB);        \
    const char* _qT = (const char*)Qm   + (size_t)(TI) * (TILE * QROWB);       \
    _Pragma("unroll")                                                          \
    for (int _j = 0; _j < 4; ++_j)                                             \
        __builtin_amdgcn_global_load_lds((gbl_ptr_t)(_pT + _j * 768 + srcPR),  \
                                         (lds_ptr_t)(&buf[BSEL][PRED0 + _j * 64]), 16, 0, 0); \
    _Pragma("unroll")                                                          \
    for (int _j = 0; _j < 4; ++_j)                                             \
        __builtin_amdgcn_global_load_lds((gbl_ptr_t)(_rT + _j * 768 + srcPR),  \
                                         (lds_ptr_t)(&buf[BSEL][R0 + _j * 64]), 16, 0, 0);    \
    __builtin_amdgcn_global_load_lds((gbl_ptr_t)(_qT + l * 16),                \
                                     (lds_ptr_t)(&buf[BSEL][Q0]), 16, 0, 0);   \
    __builtin_amdgcn_global_load_lds((gbl_ptr_t)(_qT + 1024 + (l & 31) * 4),   \
                                     (lds_ptr_t)(&buf[BSEL][Q0 + 64]), 4, 0, 0); \
} while (0)

// 3 lane-contiguous float4 loads of targ (one 32-row tile = 192 float4)
#define LOADT(TT, TI) do {                                                     \
    const char* _tT = (const char*)targ + (size_t)(TI) * (TILE * ROWB);        \
    _Pragma("unroll")                                                          \
    for (int _j = 0; _j < 3; ++_j)                                             \
        TT[_j] = *(const float4*)(_tT + (_j * 64 + l) * 16);                   \
} while (0)

// Full tile compute from buffer BSEL with targ regs TT.
// Flat phase: 3 pred chunks/lane vs TT.  Row phase: lane pair (2 lanes/row),
// each lane handles 4 tasks of row r = l>>1.
#define COMPUTE(BSEL, TT) do {                                                 \
    const float4* _pl = &buf[BSEL][PRED0];                                     \
    const float4* _rl = &buf[BSEL][R0];                                        \
    const float*  _qf = (const float*)&buf[BSEL][Q0];                          \
    /* flat: softplus + dot */                                                 \
    float _f0 = 0.0f, _f1 = 0.0f;                                              \
    _Pragma("unroll")                                                          \
    for (int _j = 0; _j < 3; ++_j) {                                           \
        float4 _x = _pl[pieceIdx[_j]];                                         \
        float4 _y = TT[_j];                                                    \
        _f0 += fmaxf(_x.x, 0.0f) + __logf(1.0f + __expf(-fabsf(_x.x))) - _x.x * _y.x; \
        _f1 += fmaxf(_x.y, 0.0f) + __logf(1.0f + __expf(-fabsf(_x.y))) - _x.y * _y.y; \
        _f0 += fmaxf(_x.z, 0.0f) + __logf(1.0f + __expf(-fabsf(_x.z))) - _x.z * _y.z; \
        _f1 += fmaxf(_x.w, 0.0f) + __logf(1.0f + __expf(-fabsf(_x.w))) - _x.w * _y.w; \
    }                                                                          \
    base_acc += (double)(_f0 + _f1);                                           \
    /* row: capability term, 4 tasks per lane */                               \
    float pv[12], rv[12];                                                      \
    _Pragma("unroll")                                                          \
    for (int _s = 0; _s < 3; ++_s) {                                           \
        float4 _v = _pl[rowBase + ((srow + _s) ^ rkey)];                       \
        pv[4 * _s + 0] = _v.x; pv[4 * _s + 1] = _v.y;                          \
        pv[4 * _s + 2] = _v.z; pv[4 * _s + 3] = _v.w;                          \
        float4 _w = _rl[rowBase + ((srow + _s) ^ rkey)];                       \
        rv[4 * _s + 0] = _w.x; rv[4 * _s + 1] = _w.y;                          \
        rv[4 * _s + 2] = _w.z; rv[4 * _s + 3] = _w.w;                          \
    }                                                                          \
    float qv[9];                                                               \
    _Pragma("unroll")                                                          \
    for (int _e = 0; _e < 9; ++_e) qv[_e] = _qf[qoff + _e];                    \
    float _cap = 0.0f;                                                         \
    _Pragma("unroll")                                                          \
    for (int _tk = 0; _tk < 4; ++_tk) {                                        \
        float _p0 = pv[_tk * 3 + 0];                                           \
        float _p1 = pv[_tk * 3 + 1];                                           \
        float _p2 = pv[_tk * 3 + 2];                                           \
        float _a0 = (_p0 > 0.5f) ? 1.0f : 0.0f;                                \
        float _a1 = (_p1 > 0.5f) ? 1.0f : 0.0f;                                \
        float _a2 = (_p2 > 0.5f) ? 1.0f : 0.0f;                                \
        float _tc0 = _a0 * qv[0] + _a1 * qv[3] + _a2 * qv[6];                  \
        float _tc1 = _a0 * qv[1] + _a1 * qv[4] + _a2 * qv[7];                  \
        float _tc2 = _a0 * qv[2] + _a1 * qv[5] + _a2 * qv[8];                  \
        float _sh  = fmaxf(rv[_tk * 3 + 0] - _tc0, 0.0f)                       \
                   + fmaxf(rv[_tk * 3 + 1] - _tc1, 0.0f)                       \
                   + fmaxf(rv[_tk * 3 + 2] - _tc2, 0.0f);                      \
        bool _active = (_p0 + _p1 + _p2) > 0.0f;                               \
        _cap += _active ? _sh : 0.0f;                                          \
    }                                                                          \
    cap_acc += (double)_cap;                                                   \
} while (0)

// ---------------------------------------------------------------------------
// Stage 1: one wave per block, 8 blocks/CU (LDS-limited), contiguous tile
// spans, double-buffered gll staging with counted vmcnt(13): stage(t+1)'s
// 13 VMEM ops stay in flight under compute(t). No barriers.
// ---------------------------------------------------------------------------
__global__ __launch_bounds__(64) void mrta_partial_kernel(
    const float* __restrict__ pred,
    const float* __restrict__ targ,
    const float* __restrict__ Rm,
    const float* __restrict__ Qm,
    double* __restrict__ partials,
    int B)
{
    __shared__ __align__(16) float4 buf[2][BUFSZ];

    const int l = threadIdx.x;   // 0..63

    // gll source pre-swizzle (dest slot d=64j+l -> row r=d>>3, r&7 == l>>3;
    // phys slot l&7 must hold source slot (l&7)^(l>>3)); verified R3/R4.
    int sfix = (l & 7) ^ (l >> 3);
    if (sfix >= 6) sfix = l & 1;                    // pad slot -> dup a valid slot
    const int srcPR = ROWB * (l >> 3) + 16 * sfix;

    // flat-phase LDS indices: chunk g=64j+l -> row g/6, slot g%6, swizzled
    int pieceIdx[3];
#pragma unroll
    for (int j = 0; j < 3; ++j) {
        int g = 64 * j + l;
        int r = g / 6, s = g - 6 * r;
        pieceIdx[j] = 8 * r + (s ^ (r & 7));
    }

    // row-phase constants: lane pair handles row r = l>>1, tasks 4h..4h+3
    const int rrow    = l >> 1;
    const int half    = l & 1;
    const int rowBase = 8 * rrow;
    const int rkey    = rrow & 7;
    const int srow    = 3 * half;       // first source slot (0 or 3)
    const int qoff    = 9 * rrow;

    double base_acc = 0.0, cap_acc = 0.0;

    const int ntiles = B / TILE;
    const int G = gridDim.x;
    const int tpb = ntiles / G, rem = ntiles % G;
    const int start = blockIdx.x * tpb + (blockIdx.x < rem ? blockIdx.x : rem);
    const int cnt = tpb + (blockIdx.x < rem ? 1 : 0);

    float4 ttA[3], ttB[3];

    if (cnt > 0) { STAGE(start, 0); LOADT(ttA, start); }

    for (int i = 0; i < cnt; i += 2) {
        if (i + 1 < cnt) {
            STAGE(start + i + 1, 1); LOADT(ttB, start + i + 1);
            SB0; WAITV13; SB0;
        } else {
            SB0; WAITV0; SB0;
        }
        COMPUTE(0, ttA);
        SB0;
        if (i + 1 < cnt) {
            if (i + 2 < cnt) {
                STAGE(start + i + 2, 0); LOADT(ttA, start + i + 2);
                SB0; WAITV13; SB0;
            } else {
                SB0; WAITV0; SB0;
            }
            COMPUTE(1, ttB);
            SB0;
        }
    }

    // ---- tail rows (B % TILE), scalar, block 0 only ----
    if (blockIdx.x == 0) {
        int row = ntiles * TILE + l;
        if (row < B) {
            const float* pr = pred + (size_t)row * ROW;
            const float* tr = targ + (size_t)row * ROW;
            const float* rr = Rm   + (size_t)row * ROW;
            const float* qr = Qm   + (size_t)row * 9;
            float base = 0.0f;
            float pv[ROW];
            for (int k = 0; k < ROW; ++k) {
                float x = pr[k];
                pv[k] = x;
                base += fmaxf(x, 0.0f) + __logf(1.0f + __expf(-fabsf(x))) - x * tr[k];
            }
            float cap = 0.0f;
            for (int tk = 0; tk < N_TASKS; ++tk) {
                float p0 = pv[tk * 3 + 0], p1 = pv[tk * 3 + 1], p2 = pv[tk * 3 + 2];
                float a0 = (p0 > 0.5f) ? 1.0f : 0.0f;
                float a1 = (p1 > 0.5f) ? 1.0f : 0.0f;
                float a2 = (p2 > 0.5f) ? 1.0f : 0.0f;
                float tc0 = a0 * qr[0] + a1 * qr[3] + a2 * qr[6];
                float tc1 = a0 * qr[1] + a1 * qr[4] + a2 * qr[7];
                float tc2 = a0 * qr[2] + a1 * qr[5] + a2 * qr[8];
                float sh  = fmaxf(rr[tk * 3 + 0] - tc0, 0.0f)
                          + fmaxf(rr[tk * 3 + 1] - tc1, 0.0f)
                          + fmaxf(rr[tk * 3 + 2] - tc2, 0.0f);
                if ((p0 + p1 + p2) > 0.0f) cap += sh;
            }
            base_acc += (double)base;
            cap_acc  += (double)cap;
        }
    }

    // ---- wave reduction, one partial pair per block ----
#pragma unroll
    for (int off = 32; off > 0; off >>= 1) {
        base_acc += __shfl_down(base_acc, off);
        cap_acc  += __shfl_down(cap_acc, off);
    }
    if (l == 0) {
        partials[blockIdx.x]             = base_acc;
        partials[gridDim.x + blockIdx.x] = cap_acc;
    }
}

// ---------------------------------------------------------------------------
// Stage 2: single-block deterministic reduction + final scalar math.
// out = {total_loss, base_loss, cap_violation, 0}
// ---------------------------------------------------------------------------
__global__ __launch_bounds__(256) void mrta_final_kernel(
    const double* __restrict__ partials,
    int nparts,
    float* __restrict__ out,
    double inv_BM,   // 1 / (B * 24)
    double inv_B)    // 1 / B
{
    double b = 0.0, c = 0.0;
    for (int i = threadIdx.x; i < nparts; i += 256) {
        b += partials[i];
        c += partials[nparts + i];
    }
#pragma unroll
    for (int off = 32; off > 0; off >>= 1) {
        b += __shfl_down(b, off);
        c += __shfl_down(c, off);
    }
    __shared__ double sb[4];
    __shared__ double sc[4];
    const int wave = threadIdx.x >> 6;
    const int lane = threadIdx.x & 63;
    if (lane == 0) { sb[wave] = b; sc[wave] = c; }
    __syncthreads();
    if (threadIdx.x == 0) {
        double bsum = sb[0] + sb[1] + sb[2] + sb[3];
        double csum = sc[0] + sc[1] + sc[2] + sc[3];
        double base = bsum * inv_BM;
        double cap  = csum * inv_B;
        double tot  = base + 0.1 * cap;
        out[0] = (float)tot;
        out[1] = (float)base;
        out[2] = (float)cap;
        out[3] = 0.0f;
    }
}

extern "C" void kernel_launch(void* const* d_in, const int* in_sizes, int n_in,
                              void* d_out, int out_size, void* d_ws, size_t ws_size,
                              hipStream_t stream) {
    const float* pred = (const float*)d_in[0];
    const float* targ = (const float*)d_in[1];
    const float* Rm   = (const float*)d_in[2];
    const float* Qm   = (const float*)d_in[3];
    float* out = (float*)d_out;

    const int B = in_sizes[0] / ROW;  // 2097152

    int blocks = 2048;
    if ((size_t)(2 * blocks) * sizeof(double) > ws_size) {
        blocks = (int)(ws_size / (2 * sizeof(double)));
        if (blocks > 2048) blocks = 2048;
        if (blocks < 1) blocks = 1;
    }

    double* partials = (double*)d_ws;

    mrta_partial_kernel<<<blocks, 64, 0, stream>>>(pred, targ, Rm, Qm, partials, B);
    mrta_final_kernel<<<1, 256, 0, stream>>>(partials, blocks, out,
                                             1.0 / ((double)B * ROW),
                                             1.0 / (double)B);
}

// Round 7
// 124.688 us; speedup vs baseline: 1.4586x; 1.0067x over previous
//
#include <hip/hip_runtime.h>

#define ROW 24            // floats per pred/targ/R row
#define ROWB 96           // bytes per row
#define TILE 32           // rows per wave-tile = 192 float4 chunks = 3 sets of 64

// ---------------------------------------------------------------------------
// Stage 1: one wave per block, zero LDS. All of pred/targ/R read as
// lane-contiguous float4 (chunk g = tile*192 + 64j + l; a chunk never crosses
// a row: row = g/6, slot s = g%6, positions 4s..4s+3). The capability term's
// task-triples are assembled from the chunk + <=2 neighbor elements on each
// side via __shfl_up/__shfl_down (+ lane-0/63 fixups across the 3 sets).
// Q is read as 9 per-lane scalars from global (adjacent lanes share rows ->
// same cache lines -> L1). Doubles accumulate; deterministic tree.
// ---------------------------------------------------------------------------
__global__ __launch_bounds__(64) void mrta_partial_kernel(
    const float* __restrict__ pred,
    const float* __restrict__ targ,
    const float* __restrict__ Rm,
    const float* __restrict__ Qm,
    double* __restrict__ partials,
    int B)
{
    const int l = threadIdx.x;   // 0..63

    // per-set lane constants (tile-independent: tile*192 is a multiple of 6)
    int sArr[3], rArr[3];
#pragma unroll
    for (int j = 0; j < 3; ++j) {
        int g = 64 * j + l;
        sArr[j] = g % 6;          // slot within row
        rArr[j] = g / 6;          // local row within tile (0..31)
    }

    double base_acc = 0.0, cap_acc = 0.0;

    const int ntiles = B / TILE;
    const int G = gridDim.x;
    const int tpb = ntiles / G, rem = ntiles % G;
    const int start = blockIdx.x * tpb + (blockIdx.x < rem ? blockIdx.x : rem);
    const int cnt = tpb + (blockIdx.x < rem ? 1 : 0);

    for (int i = 0; i < cnt; ++i) {
        const int tile = start + i;
        const char* pT = (const char*)pred + (size_t)tile * (TILE * ROWB);
        const char* tT = (const char*)targ + (size_t)tile * (TILE * ROWB);
        const char* rT = (const char*)Rm   + (size_t)tile * (TILE * ROWB);
        const float* qT = Qm + (size_t)tile * (TILE * 9);

        float4 P[3], T[3], R4[3];
#pragma unroll
        for (int j = 0; j < 3; ++j) {
            P[j]  = *(const float4*)(pT + (j * 64 + l) * 16);
            T[j]  = *(const float4*)(tT + (j * 64 + l) * 16);
            R4[j] = *(const float4*)(rT + (j * 64 + l) * 16);
        }

        float base = 0.0f, cap = 0.0f;

#pragma unroll
        for (int j = 0; j < 3; ++j) {
            const float x0 = P[j].x, x1 = P[j].y, x2 = P[j].z, x3 = P[j].w;

            // ---- flat softplus + dot (elementwise) ----
            base += fmaxf(x0, 0.0f) + __logf(1.0f + __expf(-fabsf(x0))) - x0 * T[j].x;
            base += fmaxf(x1, 0.0f) + __logf(1.0f + __expf(-fabsf(x1))) - x1 * T[j].y;
            base += fmaxf(x2, 0.0f) + __logf(1.0f + __expf(-fabsf(x2))) - x2 * T[j].z;
            base += fmaxf(x3, 0.0f) + __logf(1.0f + __expf(-fabsf(x3))) - x3 * T[j].w;

            // ---- neighbor elements (same row, adjacent chunks) ----
            float L2v = __shfl_up(P[j].z, 1);    // position 4s-2
            float L1v = __shfl_up(P[j].w, 1);    // position 4s-1
            float R1v = __shfl_down(P[j].x, 1);  // position 4s+4
            float R2v = __shfl_down(P[j].y, 1);  // position 4s+5
            if (j > 0) {                          // lane 0 gets set j-1 lane 63
                float fz = __shfl(P[j - 1].z, 63);
                float fw = __shfl(P[j - 1].w, 63);
                L2v = (l == 0) ? fz : L2v;
                L1v = (l == 0) ? fw : L1v;
            }
            if (j < 2) {                          // lane 63 gets set j+1 lane 0
                float gx = __shfl(P[j + 1].x, 0);
                float gy = __shfl(P[j + 1].y, 0);
                R1v = (l == 63) ? gx : R1v;
                R2v = (l == 63) ? gy : R2v;
            }
            // (j==0,l==0 has sm==0: L unused; j==2,l==63 has sm==2: R unused)

            const int s  = sArr[j];
            const int sm = (s >= 3) ? s - 3 : s;
            const bool m0 = (sm == 0), m1 = (sm == 1);

            // two tasks covering my 4 positions
            float tA0 = m0 ? x0 : (m1 ? L1v : L2v);
            float tA1 = m0 ? x1 : (m1 ? x0  : L1v);
            float tA2 = m0 ? x2 : (m1 ? x1  : x0 );
            float tB0 = m0 ? x3 : (m1 ? x2  : x1 );
            float tB1 = m0 ? R1v: (m1 ? x3  : x2 );
            float tB2 = m0 ? R2v: (m1 ? R1v : x3 );

            float aA0 = (tA0 > 0.5f) ? 1.0f : 0.0f;
            float aA1 = (tA1 > 0.5f) ? 1.0f : 0.0f;
            float aA2 = (tA2 > 0.5f) ? 1.0f : 0.0f;
            float aB0 = (tB0 > 0.5f) ? 1.0f : 0.0f;
            float aB1 = (tB1 > 0.5f) ? 1.0f : 0.0f;
            float aB2 = (tB2 > 0.5f) ? 1.0f : 0.0f;
            float actA = ((tA0 + tA1 + tA2) > 0.0f) ? 1.0f : 0.0f;
            float actB = ((tB0 + tB1 + tB2) > 0.0f) ? 1.0f : 0.0f;

            // this row's Q (3x3 row-major); adjacent lanes share lines -> L1
            const float* q = qT + rArr[j] * 9;
            float q0 = q[0], q1 = q[1], q2 = q[2];
            float q3 = q[3], q4 = q[4], q5 = q[5];
            float q6 = q[6], q7 = q[7], q8 = q[8];

            float tcA0 = fmaf(aA0, q0, fmaf(aA1, q3, aA2 * q6));
            float tcA1 = fmaf(aA0, q1, fmaf(aA1, q4, aA2 * q7));
            float tcA2 = fmaf(aA0, q2, fmaf(aA1, q5, aA2 * q8));
            float tcB0 = fmaf(aB0, q0, fmaf(aB1, q3, aB2 * q6));
            float tcB1 = fmaf(aB0, q1, fmaf(aB1, q4, aB2 * q7));
            float tcB2 = fmaf(aB0, q2, fmaf(aB1, q5, aB2 * q8));

            const int nA = m0 ? 3 : (m1 ? 2 : 1);
#pragma unroll
            for (int k = 0; k < 4; ++k) {
                const bool inA = (k < nA);
                float c0v = inA ? tcA0 : tcB0;
                float c1v = inA ? tcA1 : tcB1;
                float c2v = inA ? tcA2 : tcB2;
                float av  = inA ? actA : actB;
                int ck = sm + k; ck = (ck >= 3) ? ck - 3 : ck;   // (sm+k)%3
                float tc = (ck == 0) ? c0v : ((ck == 1) ? c1v : c2v);
                float Rk = (k == 0) ? R4[j].x : (k == 1) ? R4[j].y
                          : (k == 2) ? R4[j].z : R4[j].w;
                cap += av * fmaxf(Rk - tc, 0.0f);
            }
        }

        base_acc += (double)base;
        cap_acc  += (double)cap;
    }

    // ---- tail rows (B % TILE), scalar, block 0 only ----
    if (blockIdx.x == 0) {
        int row = ntiles * TILE + l;
        if (row < B) {
            const float* pr = pred + (size_t)row * ROW;
            const float* tr = targ + (size_t)row * ROW;
            const float* rr = Rm   + (size_t)row * ROW;
            const float* qr = Qm   + (size_t)row * 9;
            float base = 0.0f;
            float pv[ROW];
            for (int k = 0; k < ROW; ++k) {
                float x = pr[k];
                pv[k] = x;
                base += fmaxf(x, 0.0f) + __logf(1.0f + __expf(-fabsf(x))) - x * tr[k];
            }
            float cap = 0.0f;
            for (int tk = 0; tk < 8; ++tk) {
                float p0 = pv[tk * 3 + 0], p1 = pv[tk * 3 + 1], p2 = pv[tk * 3 + 2];
                float a0 = (p0 > 0.5f) ? 1.0f : 0.0f;
                float a1 = (p1 > 0.5f) ? 1.0f : 0.0f;
                float a2 = (p2 > 0.5f) ? 1.0f : 0.0f;
                float tc0 = a0 * qr[0] + a1 * qr[3] + a2 * qr[6];
                float tc1 = a0 * qr[1] + a1 * qr[4] + a2 * qr[7];
                float tc2 = a0 * qr[2] + a1 * qr[5] + a2 * qr[8];
                float sh  = fmaxf(rr[tk * 3 + 0] - tc0, 0.0f)
                          + fmaxf(rr[tk * 3 + 1] - tc1, 0.0f)
                          + fmaxf(rr[tk * 3 + 2] - tc2, 0.0f);
                if ((p0 + p1 + p2) > 0.0f) cap += sh;
            }
            base_acc += (double)base;
            cap_acc  += (double)cap;
        }
    }

    // ---- wave reduction, one partial pair per block ----
#pragma unroll
    for (int off = 32; off > 0; off >>= 1) {
        base_acc += __shfl_down(base_acc, off);
        cap_acc  += __shfl_down(cap_acc, off);
    }
    if (l == 0) {
        partials[blockIdx.x]             = base_acc;
        partials[gridDim.x + blockIdx.x] = cap_acc;
    }
}

// ---------------------------------------------------------------------------
// Stage 2: single-block deterministic reduction + final scalar math.
// out = {total_loss, base_loss, cap_violation, 0}
// ---------------------------------------------------------------------------
__global__ __launch_bounds__(256) void mrta_final_kernel(
    const double* __restrict__ partials,
    int nparts,
    float* __restrict__ out,
    double inv_BM,   // 1 / (B * 24)
    double inv_B)    // 1 / B
{
    double b = 0.0, c = 0.0;
    for (int i = threadIdx.x; i < nparts; i += 256) {
        b += partials[i];
        c += partials[nparts + i];
    }
#pragma unroll
    for (int off = 32; off > 0; off >>= 1) {
        b += __shfl_down(b, off);
        c += __shfl_down(c, off);
    }
    __shared__ double sb[4];
    __shared__ double sc[4];
    const int wave = threadIdx.x >> 6;
    const int lane = threadIdx.x & 63;
    if (lane == 0) { sb[wave] = b; sc[wave] = c; }
    __syncthreads();
    if (threadIdx.x == 0) {
        double bsum = sb[0] + sb[1] + sb[2] + sb[3];
        double csum = sc[0] + sc[1] + sc[2] + sc[3];
        double base = bsum * inv_BM;
        double cap  = csum * inv_B;
        double tot  = base + 0.1 * cap;
        out[0] = (float)tot;
        out[1] = (float)base;
        out[2] = (float)cap;
        out[3] = 0.0f;
    }
}

extern "C" void kernel_launch(void* const* d_in, const int* in_sizes, int n_in,
                              void* d_out, int out_size, void* d_ws, size_t ws_size,
                              hipStream_t stream) {
    const float* pred = (const float*)d_in[0];
    const float* targ = (const float*)d_in[1];
    const float* Rm   = (const float*)d_in[2];
    const float* Qm   = (const float*)d_in[3];
    float* out = (float*)d_out;

    const int B = in_sizes[0] / ROW;  // 2097152

    int blocks = 2048;
    if ((size_t)(2 * blocks) * sizeof(double) > ws_size) {
        blocks = (int)(ws_size / (2 * sizeof(double)));
        if (blocks > 2048) blocks = 2048;
        if (blocks < 1) blocks = 1;
    }

    double* partials = (double*)d_ws;

    mrta_partial_kernel<<<blocks, 64, 0, stream>>>(pred, targ, Rm, Qm, partials, B);
    mrta_final_kernel<<<1, 256, 0, stream>>>(partials, blocks, out,
                                             1.0 / ((double)B * ROW),
                                             1.0 / (double)B);
}